// Round 4
// baseline (595.263 us; speedup 1.0000x reference)
//
#include <hip/hip_runtime.h>

#define NN 256
#define LL 128
#define BSZ 16
#define NBLK 256

typedef float v2f __attribute__((ext_vector_type(2)));

// ---------------------------------------------------------------------------
// Device-scope grid barrier. Slot-per-barrier flags; works from ANY initial
// state with (int)value < n  (0xAA poison = negative, fresh zeros = 0).
// Harness re-poisons d_ws before every launch, so slots are always "unarmed".
// ---------------------------------------------------------------------------
__device__ __forceinline__ void gridbar(int n, unsigned* flags, unsigned* rel,
                                        int bid) {
    __syncthreads();
    if (threadIdx.x == 0)
        __hip_atomic_store(&flags[bid], (unsigned)n, __ATOMIC_RELEASE,
                           __HIP_MEMORY_SCOPE_AGENT);
    if (bid == 0) {
        if (threadIdx.x < NBLK) {
            while ((int)__hip_atomic_load(&flags[threadIdx.x], __ATOMIC_RELAXED,
                                          __HIP_MEMORY_SCOPE_AGENT) < n)
                __builtin_amdgcn_s_sleep(2);
        }
        __syncthreads();
        if (threadIdx.x == 0)
            __hip_atomic_store(&rel[n], (unsigned)n, __ATOMIC_RELEASE,
                               __HIP_MEMORY_SCOPE_AGENT);
    } else {
        if (threadIdx.x == 0) {
            while ((int)__hip_atomic_load(&rel[n], __ATOMIC_RELAXED,
                                          __HIP_MEMORY_SCOPE_AGENT) < n)
                __builtin_amdgcn_s_sleep(2);
        }
    }
    __builtin_amdgcn_fence(__ATOMIC_ACQUIRE, "agent");
    __syncthreads();
}

// ---------------------------------------------------------------------------
// One persistent kernel: weights transpose + 3 GCN steps with grid barriers.
// Grid MUST be 256 blocks (1/CU -> co-residency guaranteed).
// ---------------------------------------------------------------------------
__global__ __launch_bounds__(512) void fused_k(
    const float* __restrict__ feat,   // [16][128][256]
    const float* __restrict__ mask,   // [16][128]
    const float* __restrict__ aggW,   // [3][256][256]
    const float* __restrict__ aggB,   // [3][256]
    const float* __restrict__ attnW,  // [3][256][512]
    const float* __restrict__ updW,   // [3][256][512]
    const float* __restrict__ updB,   // [3][256]
    float* __restrict__ hidfix, float* __restrict__ xbuf,
    float* __restrict__ pbuf,   float* __restrict__ xU1,
    float* __restrict__ WtB,    unsigned* flags, unsigned* rel,
    float* __restrict__ out)
{
    __shared__ float lds[64 * 65];   // 16.6 KB, reused per phase
    const int bid = blockIdx.x;
    const int tid = threadIdx.x;

    // ---- P0: transpose 12 weight mats to k-major (bid<192), hidfix (>=192)
    if (bid < 192) {
        const int m = bid >> 4, t = bid & 15, tr = t >> 2, tc = t & 3;
        const float* src; int stride, off;
        if (m < 3)      { src = aggW  + (size_t)m * 65536;        stride = 256; off = 0;   }
        else if (m < 6) { src = attnW + (size_t)(m - 3) * 131072; stride = 512; off = 0;   }
        else if (m < 9) { src = updW  + (size_t)(m - 6) * 131072; stride = 512; off = 0;   }
        else            { src = updW  + (size_t)(m - 9) * 131072; stride = 512; off = 256; }
        float* dst = WtB + (size_t)m * 65536;
        #pragma unroll
        for (int i = 0; i < 2; ++i) {
            const int j = i * 512 + tid, row = j >> 4, q = (j & 15) * 4;
            const float4 v = *(const float4*)(src + (size_t)(tr * 64 + row) * stride + off + tc * 64 + q);
            lds[row * 65 + q + 0] = v.x; lds[row * 65 + q + 1] = v.y;
            lds[row * 65 + q + 2] = v.z; lds[row * 65 + q + 3] = v.w;
        }
        __syncthreads();
        #pragma unroll
        for (int i = 0; i < 2; ++i) {
            const int j = i * 512 + tid, kl = j >> 4, cq = (j & 15) * 4;
            float4 v;
            v.x = lds[(cq + 0) * 65 + kl]; v.y = lds[(cq + 1) * 65 + kl];
            v.z = lds[(cq + 2) * 65 + kl]; v.w = lds[(cq + 3) * 65 + kl];
            *(float4*)(dst + (size_t)(tc * 64 + kl) * 256 + tr * 64 + cq) = v;
        }
    } else {
        const int hb = bid - 192;                       // 64 blocks x 32 rows
        const float4* f4 = (const float4*)feat;
        float4* h4 = (float4*)hidfix;
        #pragma unroll
        for (int i = 0; i < 4; ++i) {
            const int j = hb * 2048 + i * 512 + tid;    // float4 index
            const float4 v = f4[j];
            const float mv = mask[j >> 6];
            h4[j] = make_float4(v.x * mv, v.y * mv, v.z * mv, v.w * mv);
        }
    }
    gridbar(1, flags, rel, bid);

    for (int i = 0; i < 3; ++i) {
        const int rt = bid >> 2, ct = bid & 3;
        const int c  = ct * 64 + (tid & 63);
        const int r0 = __builtin_amdgcn_readfirstlane(rt * 32 + (tid >> 6) * 4);

        // ---- P1: x = hidfix @ aggW_i^T + aggB_i
        {
            const float* Ar = hidfix + (size_t)r0 * 256;        // wave-uniform -> s_load
            const float* Wc = WtB + (size_t)i * 65536 + c;      // coalesced
            v2f acc0 = {0.f, 0.f}, acc1 = {0.f, 0.f};
            #pragma unroll 8
            for (int k = 0; k < 256; ++k) {
                const float w = Wc[k * 256];
                v2f a01 = {Ar[k], Ar[256 + k]};
                v2f a23 = {Ar[512 + k], Ar[768 + k]};
                acc0 += a01 * w; acc1 += a23 * w;
            }
            const float bb = aggB[i * 256 + c];
            xbuf[(size_t)(r0 + 0) * 256 + c] = acc0.x + bb;
            xbuf[(size_t)(r0 + 1) * 256 + c] = acc0.y + bb;
            xbuf[(size_t)(r0 + 2) * 256 + c] = acc1.x + bb;
            xbuf[(size_t)(r0 + 3) * 256 + c] = acc1.y + bb;
        }
        gridbar(3 * i + 2, flags, rel, bid);

        // ---- P2: p = x @ W1^T ; xU1 = x @ U1^T
        {
            const float* Ar  = xbuf + (size_t)r0 * 256;
            const float* W1c = WtB + (size_t)(3 + i) * 65536 + c;
            const float* U1c = WtB + (size_t)(6 + i) * 65536 + c;
            v2f p0 = {0.f, 0.f}, p1 = {0.f, 0.f}, u0 = {0.f, 0.f}, u1 = {0.f, 0.f};
            #pragma unroll 8
            for (int k = 0; k < 256; ++k) {
                const float w1 = W1c[k * 256];
                const float q1 = U1c[k * 256];
                v2f a01 = {Ar[k], Ar[256 + k]};
                v2f a23 = {Ar[512 + k], Ar[768 + k]};
                p0 += a01 * w1; p1 += a23 * w1;
                u0 += a01 * q1; u1 += a23 * q1;
            }
            pbuf[(size_t)(r0 + 0) * 256 + c] = p0.x;
            pbuf[(size_t)(r0 + 1) * 256 + c] = p0.y;
            pbuf[(size_t)(r0 + 2) * 256 + c] = p1.x;
            pbuf[(size_t)(r0 + 3) * 256 + c] = p1.y;
            xU1 [(size_t)(r0 + 0) * 256 + c] = u0.x;
            xU1 [(size_t)(r0 + 1) * 256 + c] = u0.y;
            xU1 [(size_t)(r0 + 2) * 256 + c] = u1.x;
            xU1 [(size_t)(r0 + 3) * 256 + c] = u1.y;
        }
        gridbar(3 * i + 3, flags, rel, bid);

        // ---- P3+P5: softmax_s(p).x -> sigmoid -> @U2^T + updB -> fix/out
        {
            const int b = bid >> 4, sc = bid & 15, s0v = sc * 8;
            const int cc = tid & 255, sh = tid >> 8;
            const float* pp = pbuf + (size_t)(b * 128 + sh * 64) * 256 + cc;
            const float* xx = xbuf + (size_t)(b * 128 + sh * 64) * 256 + cc;
            float m = -1e30f, den = 0.f, num = 0.f;
            #pragma unroll 4
            for (int s = 0; s < 64; ++s) {
                const float pv = pp[s * 256], xv = xx[s * 256];
                const float mn = fmaxf(m, pv);
                const float scl = __expf(m - mn);
                const float ev  = __expf(pv - mn);
                den = den * scl + ev;
                num = num * scl + ev * xv;
                m = mn;
            }
            lds[sh * 256 + cc] = m;
            lds[512 + sh * 256 + cc] = den;
            lds[1024 + sh * 256 + cc] = num;
            __syncthreads();
            if (tid < 256) {
                const float m0 = lds[tid], m1 = lds[256 + tid];
                const float M = fmaxf(m0, m1);
                const float e0 = __expf(m0 - M), e1 = __expf(m1 - M);
                const float d = lds[512 + tid] * e0 + lds[768 + tid] * e1;
                const float nm = lds[1024 + tid] * e0 + lds[1280 + tid] * e1;
                lds[1536 + tid] = 1.f / (1.f + __expf(-(nm / d)));
            }
            __syncthreads();
            const float* U2c = WtB + (size_t)(9 + i) * 65536 + cc;
            float au = 0.f;
            #pragma unroll 4
            for (int j = sh * 128; j < sh * 128 + 128; ++j)
                au += lds[1536 + j] * U2c[j * 256];
            lds[2048 + sh * 256 + cc] = au;
            __syncthreads();
            if (sh == 0) {
                const float accU = lds[2048 + cc] + lds[2304 + cc] + updB[i * 256 + cc];
                const int rowb = b * 128 + s0v;
                if (i < 2) {
                    #pragma unroll
                    for (int s = 0; s < 8; ++s) {
                        const int row = rowb + s;
                        hidfix[(size_t)row * 256 + cc] =
                            (xU1[(size_t)row * 256 + cc] + accU) * mask[row];
                    }
                } else {
                    #pragma unroll
                    for (int s = 0; s < 8; ++s) {
                        const int row = rowb + s;
                        out[(size_t)row * 256 + cc] = xU1[(size_t)row * 256 + cc] + accU;
                    }
                }
            }
        }
        if (i < 2) gridbar(3 * i + 4, flags, rel, bid);
    }
}

extern "C" void kernel_launch(void* const* d_in, const int* in_sizes, int n_in,
                              void* d_out, int out_size, void* d_ws, size_t ws_size,
                              hipStream_t stream) {
    const float* feat  = (const float*)d_in[0];
    const float* mask  = (const float*)d_in[1];
    const float* aggW  = (const float*)d_in[2];
    const float* aggB  = (const float*)d_in[3];
    const float* attnW = (const float*)d_in[4];
    // d_in[5] = attnB: cancels in softmax (constant along the s axis)
    const float* updW  = (const float*)d_in[6];
    const float* updB  = (const float*)d_in[7];

    const size_t MAT = (size_t)2048 * 256;   // 524288
    float* hidfix = (float*)d_ws;
    float* xbuf   = hidfix + MAT;
    float* pbuf   = xbuf + MAT;
    float* xU1    = pbuf + MAT;
    float* WtB    = xU1 + MAT;               // 12 * 65536
    unsigned* flags = (unsigned*)(WtB + 12 * 65536);
    unsigned* rel   = flags + NBLK;

    fused_k<<<NBLK, 512, 0, stream>>>(
        feat, mask, aggW, aggB, attnW, updW, updB,
        hidfix, xbuf, pbuf, xU1, WtB, flags, rel, (float*)d_out);
}

// Round 5
// 459.342 us; speedup vs baseline: 1.2959x; 1.2959x over previous
//
#include <hip/hip_runtime.h>

#define NBLK 256
#define FPAD 16   // 16 uints = 64 B -> one cacheline per flag slot

typedef float v2f __attribute__((ext_vector_type(2)));

// ---------------------------------------------------------------------------
// Fan-out grid barrier. Arrival: one 64B-padded flag word per block (no line
// sharing). Release: 16 lines 64B apart, <=16 pollers each. Works from ANY
// initial state with (int)value < n (0xAA poison is negative; zeros are 0).
// ---------------------------------------------------------------------------
__device__ __forceinline__ void gridbar(int n, unsigned* flags, unsigned* rel,
                                        int bid) {
    __syncthreads();
    if (threadIdx.x == 0)
        __hip_atomic_store(&flags[bid * FPAD], (unsigned)n, __ATOMIC_RELEASE,
                           __HIP_MEMORY_SCOPE_AGENT);
    if (bid == 0) {
        if (threadIdx.x < NBLK) {
            while ((int)__hip_atomic_load(&flags[threadIdx.x * FPAD],
                                          __ATOMIC_RELAXED,
                                          __HIP_MEMORY_SCOPE_AGENT) < n)
                __builtin_amdgcn_s_sleep(2);
        }
        __syncthreads();
        if (threadIdx.x < 16)
            __hip_atomic_store(&rel[(n * 16 + threadIdx.x) * FPAD], (unsigned)n,
                               __ATOMIC_RELEASE, __HIP_MEMORY_SCOPE_AGENT);
    } else {
        if (threadIdx.x == 0) {
            while ((int)__hip_atomic_load(&rel[(n * 16 + (bid & 15)) * FPAD],
                                          __ATOMIC_RELAXED,
                                          __HIP_MEMORY_SCOPE_AGENT) < n)
                __builtin_amdgcn_s_sleep(2);
        }
    }
    __builtin_amdgcn_fence(__ATOMIC_ACQUIRE, "agent");
    __syncthreads();
}

// ---------------------------------------------------------------------------
// One persistent kernel: weights transpose + 3 GCN steps with grid barriers.
// Grid MUST be 256 blocks (1/CU -> co-residency; empirically verified R4).
// ---------------------------------------------------------------------------
__global__ __launch_bounds__(512) void fused_k(
    const float* __restrict__ feat,   // [16][128][256]
    const float* __restrict__ mask,   // [16][128]
    const float* __restrict__ aggW,   // [3][256][256]
    const float* __restrict__ aggB,   // [3][256]
    const float* __restrict__ attnW,  // [3][256][512]
    const float* __restrict__ updW,   // [3][256][512]
    const float* __restrict__ updB,   // [3][256]
    float* __restrict__ hidfix, float* __restrict__ xbuf,
    float* __restrict__ pbuf,   float* __restrict__ xU1,
    float* __restrict__ WtB,    unsigned* flags, unsigned* rel,
    float* __restrict__ out)
{
    __shared__ float lds[64 * 65];   // 16.6 KB, reused per phase
    const int bid = blockIdx.x;
    const int tid = threadIdx.x;

    // ---- P0: transpose 12 weight mats to k-major (bid<192), hidfix (>=192)
    if (bid < 192) {
        const int m = bid >> 4, t = bid & 15, tr = t >> 2, tc = t & 3;
        const float* src; int stride, off;
        if (m < 3)      { src = aggW  + (size_t)m * 65536;        stride = 256; off = 0;   }
        else if (m < 6) { src = attnW + (size_t)(m - 3) * 131072; stride = 512; off = 0;   }
        else if (m < 9) { src = updW  + (size_t)(m - 6) * 131072; stride = 512; off = 0;   }
        else            { src = updW  + (size_t)(m - 9) * 131072; stride = 512; off = 256; }
        float* dst = WtB + (size_t)m * 65536;
        #pragma unroll
        for (int i = 0; i < 2; ++i) {
            const int j = i * 512 + tid, row = j >> 4, q = (j & 15) * 4;
            const float4 v = *(const float4*)(src + (size_t)(tr * 64 + row) * stride + off + tc * 64 + q);
            lds[row * 65 + q + 0] = v.x; lds[row * 65 + q + 1] = v.y;
            lds[row * 65 + q + 2] = v.z; lds[row * 65 + q + 3] = v.w;
        }
        __syncthreads();
        #pragma unroll
        for (int i = 0; i < 2; ++i) {
            const int j = i * 512 + tid, kl = j >> 4, cq = (j & 15) * 4;
            float4 v;
            v.x = lds[(cq + 0) * 65 + kl]; v.y = lds[(cq + 1) * 65 + kl];
            v.z = lds[(cq + 2) * 65 + kl]; v.w = lds[(cq + 3) * 65 + kl];
            *(float4*)(dst + (size_t)(tc * 64 + kl) * 256 + tr * 64 + cq) = v;
        }
    } else {
        const int hb = bid - 192;                       // 64 blocks x 32 rows
        const float4* f4 = (const float4*)feat;
        float4* h4 = (float4*)hidfix;
        #pragma unroll
        for (int i = 0; i < 4; ++i) {
            const int j = hb * 2048 + i * 512 + tid;    // float4 index
            const float4 v = f4[j];
            const float mv = mask[j >> 6];
            h4[j] = make_float4(v.x * mv, v.y * mv, v.z * mv, v.w * mv);
        }
    }
    gridbar(1, flags, rel, bid);

    for (int i = 0; i < 3; ++i) {
        const int rt = bid >> 2, ct = bid & 3;
        const int c  = ct * 64 + (tid & 63);
        const int r0 = __builtin_amdgcn_readfirstlane(rt * 32 + (tid >> 6) * 4);

        // ---- P1: x = hidfix @ aggW_i^T + aggB_i
        {
            const float* Ar = hidfix + (size_t)r0 * 256;        // uniform -> s_load
            const float* Wc = WtB + (size_t)i * 65536 + c;      // coalesced
            v2f acc0 = {0.f, 0.f}, acc1 = {0.f, 0.f};
            #pragma unroll 8
            for (int k = 0; k < 256; ++k) {
                const float w = Wc[k * 256];
                v2f a01 = {Ar[k], Ar[256 + k]};
                v2f a23 = {Ar[512 + k], Ar[768 + k]};
                acc0 += a01 * w; acc1 += a23 * w;
            }
            const float bb = aggB[i * 256 + c];
            xbuf[(size_t)(r0 + 0) * 256 + c] = acc0.x + bb;
            xbuf[(size_t)(r0 + 1) * 256 + c] = acc0.y + bb;
            xbuf[(size_t)(r0 + 2) * 256 + c] = acc1.x + bb;
            xbuf[(size_t)(r0 + 3) * 256 + c] = acc1.y + bb;
        }
        gridbar(3 * i + 2, flags, rel, bid);

        // ---- P2: p = x @ W1^T ; xU1 = x @ U1^T
        {
            const float* Ar  = xbuf + (size_t)r0 * 256;
            const float* W1c = WtB + (size_t)(3 + i) * 65536 + c;
            const float* U1c = WtB + (size_t)(6 + i) * 65536 + c;
            v2f p0 = {0.f, 0.f}, p1 = {0.f, 0.f}, u0 = {0.f, 0.f}, u1 = {0.f, 0.f};
            #pragma unroll 8
            for (int k = 0; k < 256; ++k) {
                const float w1 = W1c[k * 256];
                const float q1 = U1c[k * 256];
                v2f a01 = {Ar[k], Ar[256 + k]};
                v2f a23 = {Ar[512 + k], Ar[768 + k]};
                p0 += a01 * w1; p1 += a23 * w1;
                u0 += a01 * q1; u1 += a23 * q1;
            }
            pbuf[(size_t)(r0 + 0) * 256 + c] = p0.x;
            pbuf[(size_t)(r0 + 1) * 256 + c] = p0.y;
            pbuf[(size_t)(r0 + 2) * 256 + c] = p1.x;
            pbuf[(size_t)(r0 + 3) * 256 + c] = p1.y;
            xU1 [(size_t)(r0 + 0) * 256 + c] = u0.x;
            xU1 [(size_t)(r0 + 1) * 256 + c] = u0.y;
            xU1 [(size_t)(r0 + 2) * 256 + c] = u1.x;
            xU1 [(size_t)(r0 + 3) * 256 + c] = u1.y;
        }
        gridbar(3 * i + 3, flags, rel, bid);

        // ---- P3: blocks 0..15 only (one per batch, no redundancy):
        // softmax_s(p).x -> sigmoid -> @U2^T + updB -> write full 128-row slab
        if (bid < 16) {
            const int b = bid;
            const int cc = tid & 255, sh = tid >> 8;
            const float* pp = pbuf + (size_t)(b * 128 + sh * 64) * 256 + cc;
            const float* xx = xbuf + (size_t)(b * 128 + sh * 64) * 256 + cc;
            float m = -1e30f, den = 0.f, num = 0.f;
            #pragma unroll 4
            for (int s = 0; s < 64; ++s) {
                const float pv = pp[s * 256], xv = xx[s * 256];
                const float mn = fmaxf(m, pv);
                const float scl = __expf(m - mn);
                const float ev  = __expf(pv - mn);
                den = den * scl + ev;
                num = num * scl + ev * xv;
                m = mn;
            }
            lds[sh * 256 + cc] = m;
            lds[512 + sh * 256 + cc] = den;
            lds[1024 + sh * 256 + cc] = num;
            __syncthreads();
            if (tid < 256) {
                const float m0 = lds[tid], m1 = lds[256 + tid];
                const float M = fmaxf(m0, m1);
                const float e0 = __expf(m0 - M), e1 = __expf(m1 - M);
                const float d = lds[512 + tid] * e0 + lds[768 + tid] * e1;
                const float nm = lds[1024 + tid] * e0 + lds[1280 + tid] * e1;
                lds[1536 + tid] = 1.f / (1.f + __expf(-(nm / d)));
            }
            __syncthreads();
            const float* U2c = WtB + (size_t)(9 + i) * 65536 + cc;
            float au = 0.f;
            #pragma unroll 4
            for (int j = sh * 128; j < sh * 128 + 128; ++j)
                au += lds[1536 + j] * U2c[j * 256];
            lds[2048 + sh * 256 + cc] = au;
            __syncthreads();
            if (tid < 256)
                lds[1536 + tid] = lds[2048 + tid] + lds[2304 + tid] + updB[i * 256 + tid];
            __syncthreads();
            const float4* xu4 = (const float4*)(xU1 + (size_t)b * 128 * 256);
            if (i < 2) {
                float4* h4 = (float4*)(hidfix + (size_t)b * 128 * 256);
                #pragma unroll
                for (int t = 0; t < 16; ++t) {
                    const int idx = t * 512 + tid;          // 0..8191 float4s
                    const int row = idx >> 6, cq = (idx & 63) * 4;
                    const float4 v = xu4[idx];
                    const float4 a = *(const float4*)&lds[1536 + cq];
                    const float mv = mask[b * 128 + row];
                    h4[idx] = make_float4((v.x + a.x) * mv, (v.y + a.y) * mv,
                                          (v.z + a.z) * mv, (v.w + a.w) * mv);
                }
            } else {
                float4* o4 = (float4*)(out + (size_t)b * 128 * 256);
                #pragma unroll
                for (int t = 0; t < 16; ++t) {
                    const int idx = t * 512 + tid;
                    const int cq = (idx & 63) * 4;
                    const float4 v = xu4[idx];
                    const float4 a = *(const float4*)&lds[1536 + cq];
                    o4[idx] = make_float4(v.x + a.x, v.y + a.y,
                                          v.z + a.z, v.w + a.w);
                }
            }
        }
        if (i < 2) gridbar(3 * i + 4, flags, rel, bid);
    }
}

extern "C" void kernel_launch(void* const* d_in, const int* in_sizes, int n_in,
                              void* d_out, int out_size, void* d_ws, size_t ws_size,
                              hipStream_t stream) {
    const float* feat  = (const float*)d_in[0];
    const float* mask  = (const float*)d_in[1];
    const float* aggW  = (const float*)d_in[2];
    const float* aggB  = (const float*)d_in[3];
    const float* attnW = (const float*)d_in[4];
    // d_in[5] = attnB: cancels in softmax (constant along the s axis)
    const float* updW  = (const float*)d_in[6];
    const float* updB  = (const float*)d_in[7];

    const size_t MAT = (size_t)2048 * 256;   // 524288
    float* hidfix = (float*)d_ws;
    float* xbuf   = hidfix + MAT;
    float* pbuf   = xbuf + MAT;
    float* xU1    = pbuf + MAT;
    float* WtB    = xU1 + MAT;               // 12 * 65536
    unsigned* flags = (unsigned*)(WtB + 12 * 65536);   // 256 * 64B
    unsigned* rel   = flags + NBLK * FPAD;             // 10 barriers * 16 lines

    fused_k<<<NBLK, 512, 0, stream>>>(
        feat, mask, aggW, aggB, attnW, updW, updB,
        hidfix, xbuf, pbuf, xU1, WtB, flags, rel, (float*)d_out);
}

// Round 6
// 251.605 us; speedup vs baseline: 2.3659x; 1.8256x over previous
//
#include <hip/hip_runtime.h>

#define NBLK 256
#define FPAD 16   // 64 B per flag slot

typedef float v2f __attribute__((ext_vector_type(2)));

// Fan-out grid barrier (validated R5). Works from any initial state with
// (int)value < n (0xAA poison negative, zeros 0). Release fans to 16 lines.
__device__ __forceinline__ void gridbar(int n, unsigned* flags, unsigned* rel,
                                        int bid) {
    __syncthreads();
    if (threadIdx.x == 0)
        __hip_atomic_store(&flags[bid * FPAD], (unsigned)n, __ATOMIC_RELEASE,
                           __HIP_MEMORY_SCOPE_AGENT);
    if (bid == 0) {
        if (threadIdx.x < NBLK) {
            while ((int)__hip_atomic_load(&flags[threadIdx.x * FPAD],
                                          __ATOMIC_RELAXED,
                                          __HIP_MEMORY_SCOPE_AGENT) < n)
                __builtin_amdgcn_s_sleep(1);
        }
        __syncthreads();
        if (threadIdx.x < 16)
            __hip_atomic_store(&rel[(n * 16 + threadIdx.x) * FPAD], (unsigned)n,
                               __ATOMIC_RELEASE, __HIP_MEMORY_SCOPE_AGENT);
    } else {
        if (threadIdx.x == 0) {
            while ((int)__hip_atomic_load(&rel[(n * 16 + (bid & 15)) * FPAD],
                                          __ATOMIC_RELAXED,
                                          __HIP_MEMORY_SCOPE_AGENT) < n)
                __builtin_amdgcn_s_sleep(1);
        }
    }
    __builtin_amdgcn_fence(__ATOMIC_ACQUIRE, "agent");
    __syncthreads();
}

// Redundant per-block softmax-combine + U2 matvec for batch b, step i.
// Reads 16 producer partials (3x256 each), returns accU[c] = agg@U2^T + updB.
// Executed by ALL threads of the block (contains __syncthreads).
__device__ __forceinline__ float phaseB(int i, int b, int c, int rq,
                                        const float* __restrict__ part,
                                        const float* __restrict__ WtB,
                                        const float* __restrict__ updB,
                                        float* sc, float* aggl) {
    float M = -1e30f, den = 0.f, num = 0.f;
    const int par = i & 1;
    #pragma unroll
    for (int j = rq * 8; j < rq * 8 + 8; ++j) {
        const float* pp = part + ((size_t)(par * 256 + b * 16 + j) * 3) * 256;
        const float mj = pp[c], dj = pp[256 + c], nj = pp[512 + c];
        const float Mn = fmaxf(M, mj);
        const float s = __expf(M - Mn), e = __expf(mj - Mn);
        den = den * s + dj * e;
        num = num * s + nj * e;
        M = Mn;
    }
    sc[rq * 256 + c] = M;
    sc[512 + rq * 256 + c] = den;
    sc[1024 + rq * 256 + c] = num;
    __syncthreads();
    if (rq == 0) {
        const float m0 = sc[c], m1 = sc[256 + c];
        const float Mx = fmaxf(m0, m1);
        const float s0 = __expf(m0 - Mx), s1 = __expf(m1 - Mx);
        const float dd = sc[512 + c] * s0 + sc[768 + c] * s1;
        const float nn = sc[1024 + c] * s0 + sc[1280 + c] * s1;
        aggl[c] = 1.f / (1.f + __expf(-(nn / dd)));
    }
    __syncthreads();
    const float* U2c = WtB + (size_t)(9 + i) * 65536 + c;
    float au = 0.f;
    #pragma unroll 8
    for (int k = rq * 128; k < rq * 128 + 128; ++k)
        au += aggl[k] * U2c[(size_t)k * 256];
    __syncthreads();
    sc[rq * 256 + c] = au;
    __syncthreads();
    return sc[c] + sc[256 + c] + updB[i * 256 + c];
}

// Persistent kernel. Block bid = (batch b = bid>>4, octet j = bid&15) owns
// rows b*128+j*8 .. +8. All intermediates for those rows stay block-local;
// only 3 KB softmax partials cross each barrier. 4 barriers total.
__global__ __launch_bounds__(512) void fused_k(
    const float* __restrict__ feat,   // [16][128][256]
    const float* __restrict__ mask,   // [16][128]
    const float* __restrict__ aggW,   // [3][256][256]
    const float* __restrict__ aggB,   // [3][256]
    const float* __restrict__ attnW,  // [3][256][512]
    const float* __restrict__ updW,   // [3][256][512]
    const float* __restrict__ updB,   // [3][256]
    float* __restrict__ WtB,          // 12 * 65536
    float* __restrict__ part,         // 2 * 256 * 3 * 256
    unsigned* flags, unsigned* rel,
    float* __restrict__ out)
{
    __shared__ float ldsa[5888];      // hidl 0..2047 | xl 2048..4095 | sc | aggl
    float* hidl = ldsa;
    float* xl   = ldsa + 2048;
    float* sc   = ldsa + 4096;
    float* aggl = ldsa + 5632;

    const int bid = blockIdx.x;
    const int tid = threadIdx.x;
    const int c  = tid & 255;
    const int rq = tid >> 8;                 // wave-uniform
    const int b  = bid >> 4, jj = bid & 15;
    const int rbase = b * 128 + jj * 8 + rq * 4;   // first of this thread's 4 rows

    // ---- P0: transpose 12 weight mats to k-major (192 blocks; rest idle)
    if (bid < 192) {
        const int m = bid >> 4, t = bid & 15, tr = t >> 2, tc = t & 3;
        const float* src; int stride, off;
        if (m < 3)      { src = aggW  + (size_t)m * 65536;        stride = 256; off = 0;   }
        else if (m < 6) { src = attnW + (size_t)(m - 3) * 131072; stride = 512; off = 0;   }
        else if (m < 9) { src = updW  + (size_t)(m - 6) * 131072; stride = 512; off = 0;   }
        else            { src = updW  + (size_t)(m - 9) * 131072; stride = 512; off = 256; }
        float* dst = WtB + (size_t)m * 65536;
        #pragma unroll
        for (int it = 0; it < 2; ++it) {
            const int j = it * 512 + tid, row = j >> 4, q = (j & 15) * 4;
            const float4 v = *(const float4*)(src + (size_t)(tr * 64 + row) * stride + off + tc * 64 + q);
            ldsa[row * 65 + q + 0] = v.x; ldsa[row * 65 + q + 1] = v.y;
            ldsa[row * 65 + q + 2] = v.z; ldsa[row * 65 + q + 3] = v.w;
        }
        __syncthreads();
        #pragma unroll
        for (int it = 0; it < 2; ++it) {
            const int j = it * 512 + tid, kl = j >> 4, cq = (j & 15) * 4;
            float4 v;
            v.x = ldsa[(cq + 0) * 65 + kl]; v.y = ldsa[(cq + 1) * 65 + kl];
            v.z = ldsa[(cq + 2) * 65 + kl]; v.w = ldsa[(cq + 3) * 65 + kl];
            *(float4*)(dst + (size_t)(tc * 64 + kl) * 256 + tr * 64 + cq) = v;
        }
    }
    gridbar(1, flags, rel, bid);

    float xu0 = 0.f, xu1 = 0.f, xu2 = 0.f, xu3 = 0.f;
    float accU = 0.f;

    for (int i = 0; i < 3; ++i) {
        // ---- phase B for previous step (redundant per block, no extra barrier)
        if (i > 0)
            accU = phaseB(i - 1, b, c, rq, part, WtB, updB, sc, aggl);

        // ---- build hid rows in LDS (layout [k=c][row 0..7])
        if (i == 0) {
            #pragma unroll
            for (int r = 0; r < 4; ++r)
                hidl[c * 8 + rq * 4 + r] =
                    feat[(size_t)(rbase + r) * 256 + c] * mask[rbase + r];
        } else {
            const float xur[4] = {xu0, xu1, xu2, xu3};
            #pragma unroll
            for (int r = 0; r < 4; ++r)
                hidl[c * 8 + rq * 4 + r] = (xur[r] + accU) * mask[rbase + r];
        }
        __syncthreads();

        // ---- x = hid @ aggW^T + aggB  (weights streamed, hid via LDS broadcast)
        v2f xa0 = {0.f, 0.f}, xa1 = {0.f, 0.f};
        const float* Wc = WtB + (size_t)i * 65536 + c;
        #pragma unroll 8
        for (int k = 0; k < 256; ++k) {
            const float w = Wc[(size_t)k * 256];
            const float4 h = *(const float4*)&hidl[k * 8 + rq * 4];
            xa0 += (v2f){h.x, h.y} * w;
            xa1 += (v2f){h.z, h.w} * w;
        }
        const float bb = aggB[i * 256 + c];
        const float x0 = xa0.x + bb, x1 = xa0.y + bb;
        const float x2 = xa1.x + bb, x3 = xa1.y + bb;
        *(float4*)&xl[c * 8 + rq * 4] = make_float4(x0, x1, x2, x3);
        __syncthreads();

        // ---- p = x@W1^T (regs), xU1 = x@U1^T (regs, persists across barrier)
        v2f p0 = {0.f, 0.f}, p1 = {0.f, 0.f}, u0 = {0.f, 0.f}, u1 = {0.f, 0.f};
        const float* W1c = WtB + (size_t)(3 + i) * 65536 + c;
        const float* U1c = WtB + (size_t)(6 + i) * 65536 + c;
        #pragma unroll 8
        for (int k = 0; k < 256; ++k) {
            const float w1 = W1c[(size_t)k * 256];
            const float q1 = U1c[(size_t)k * 256];
            const float4 xk = *(const float4*)&xl[k * 8 + rq * 4];
            p0 += (v2f){xk.x, xk.y} * w1;
            p1 += (v2f){xk.z, xk.w} * w1;
            u0 += (v2f){xk.x, xk.y} * q1;
            u1 += (v2f){xk.z, xk.w} * q1;
        }
        xu0 = u0.x; xu1 = u0.y; xu2 = u1.x; xu3 = u1.y;

        // ---- online-softmax partials over this thread's 4 rows
        const float m4 = fmaxf(fmaxf(p0.x, p0.y), fmaxf(p1.x, p1.y));
        const float e0 = __expf(p0.x - m4), e1 = __expf(p0.y - m4);
        const float e2 = __expf(p1.x - m4), e3 = __expf(p1.y - m4);
        const float d4 = e0 + e1 + e2 + e3;
        const float n4 = e0 * x0 + e1 * x1 + e2 * x2 + e3 * x3;
        __syncthreads();
        sc[rq * 256 + c] = m4;
        sc[512 + rq * 256 + c] = d4;
        sc[1024 + rq * 256 + c] = n4;
        __syncthreads();
        if (rq == 0) {
            const float m0 = sc[c], m1 = sc[256 + c];
            const float Mx = fmaxf(m0, m1);
            const float s0 = __expf(m0 - Mx), s1 = __expf(m1 - Mx);
            const float dd = sc[512 + c] * s0 + sc[768 + c] * s1;
            const float nn = sc[1024 + c] * s0 + sc[1280 + c] * s1;
            float* pb = part + ((size_t)((i & 1) * 256 + bid) * 3) * 256;
            pb[c] = Mx; pb[256 + c] = dd; pb[512 + c] = nn;
        }
        gridbar(i + 2, flags, rel, bid);
    }

    // ---- final phase B (step 2) + epilogue: out = xU1 + accU
    accU = phaseB(2, b, c, rq, part, WtB, updB, sc, aggl);
    const float xur[4] = {xu0, xu1, xu2, xu3};
    #pragma unroll
    for (int r = 0; r < 4; ++r)
        out[(size_t)(rbase + r) * 256 + c] = xur[r] + accU;
}

extern "C" void kernel_launch(void* const* d_in, const int* in_sizes, int n_in,
                              void* d_out, int out_size, void* d_ws, size_t ws_size,
                              hipStream_t stream) {
    const float* feat  = (const float*)d_in[0];
    const float* mask  = (const float*)d_in[1];
    const float* aggW  = (const float*)d_in[2];
    const float* aggB  = (const float*)d_in[3];
    const float* attnW = (const float*)d_in[4];
    // d_in[5] = attnB: cancels in softmax (constant along the s axis)
    const float* updW  = (const float*)d_in[6];
    const float* updB  = (const float*)d_in[7];

    float* WtB  = (float*)d_ws;                        // 12 * 65536 floats
    float* part = WtB + 12 * 65536;                    // 2*256*3*256 floats
    unsigned* flags = (unsigned*)(part + 2 * 256 * 3 * 256);
    unsigned* rel   = flags + NBLK * FPAD;

    fused_k<<<NBLK, 512, 0, stream>>>(
        feat, mask, aggW, aggB, attnW, updW, updB,
        WtB, part, flags, rel, (float*)d_out);
}

// Round 7
// 169.326 us; speedup vs baseline: 3.5155x; 1.4859x over previous
//
#include <hip/hip_runtime.h>

#define NBLK 256
#define FPAD 16   // 64 B per flag slot

typedef float v2f __attribute__((ext_vector_type(2)));

#define AG_LD(p)    __hip_atomic_load((p), __ATOMIC_RELAXED, __HIP_MEMORY_SCOPE_AGENT)
#define AG_ST(p, v) __hip_atomic_store((p), (v), __ATOMIC_RELAXED, __HIP_MEMORY_SCOPE_AGENT)

// Fan-out grid barrier (validated R5/R6). fence=true only where we must
// invalidate stale L2 (after the transpose phase); data that crosses the
// other barriers travels via agent-scope atomics instead, so the weights
// stay L2-resident across steps.
__device__ __forceinline__ void gridbar(int n, unsigned* flags, unsigned* rel,
                                        int bid, bool fence) {
    __syncthreads();
    if (threadIdx.x == 0)
        __hip_atomic_store(&flags[bid * FPAD], (unsigned)n, __ATOMIC_RELEASE,
                           __HIP_MEMORY_SCOPE_AGENT);
    if (bid == 0) {
        if (threadIdx.x < NBLK) {
            while ((int)__hip_atomic_load(&flags[threadIdx.x * FPAD],
                                          __ATOMIC_RELAXED,
                                          __HIP_MEMORY_SCOPE_AGENT) < n)
                __builtin_amdgcn_s_sleep(1);
        }
        __syncthreads();
        if (threadIdx.x < 16)
            __hip_atomic_store(&rel[(n * 16 + threadIdx.x) * FPAD], (unsigned)n,
                               __ATOMIC_RELEASE, __HIP_MEMORY_SCOPE_AGENT);
    } else {
        if (threadIdx.x == 0) {
            while ((int)__hip_atomic_load(&rel[(n * 16 + (bid & 15)) * FPAD],
                                          __ATOMIC_RELAXED,
                                          __HIP_MEMORY_SCOPE_AGENT) < n)
                __builtin_amdgcn_s_sleep(1);
        }
    }
    if (fence) __builtin_amdgcn_fence(__ATOMIC_ACQUIRE, "agent");
    __syncthreads();
}

// Per-batch softmax-combine (16 partial records via agent atomics) + sigmoid
// + U2 matvec (register-pipelined weight stream) + updB. Redundant per block.
__device__ __forceinline__ float phaseB(int i, int b, int c, int rq,
                                        const float* __restrict__ part,
                                        const float* __restrict__ WtB,
                                        const float* __restrict__ updB,
                                        float* sc, float* aggl) {
    float M = -1e30f, den = 0.f, num = 0.f;
    const int par = i & 1;
    #pragma unroll
    for (int j = rq * 8; j < rq * 8 + 8; ++j) {
        const float* pp = part + (size_t)(par * 256 + b * 16 + j) * 768;
        const float mj = AG_LD(pp + c);
        const float dj = AG_LD(pp + 256 + c);
        const float nj = AG_LD(pp + 512 + c);
        const float Mn = fmaxf(M, mj);
        const float s = __expf(M - Mn), e = __expf(mj - Mn);
        den = den * s + dj * e;
        num = num * s + nj * e;
        M = Mn;
    }
    sc[rq * 256 + c] = M;
    sc[512 + rq * 256 + c] = den;
    sc[1024 + rq * 256 + c] = num;
    __syncthreads();
    if (rq == 0) {
        const float m0 = sc[c], m1 = sc[256 + c];
        const float Mx = fmaxf(m0, m1);
        const float s0 = __expf(m0 - Mx), s1 = __expf(m1 - Mx);
        const float dd = sc[512 + c] * s0 + sc[768 + c] * s1;
        const float nn = sc[1024 + c] * s0 + sc[1280 + c] * s1;
        aggl[c] = 1.f / (1.f + __expf(-(nn / dd)));
    }
    __syncthreads();
    // U2 matvec: 128 k per thread (split by rq), depth-2 octet pipeline
    const float* U2c = WtB + (size_t)(9 + i) * 65536 + (size_t)rq * 128 * 256 + c;
    const float* ag = aggl + rq * 128;
    float wa[8], wb[8];
    #pragma unroll
    for (int j = 0; j < 8; ++j) wa[j] = U2c[(size_t)j * 256];
    float au = 0.f;
    for (int o2 = 0; o2 < 8; ++o2) {
        #pragma unroll
        for (int j = 0; j < 8; ++j) wb[j] = U2c[(size_t)(o2 * 16 + 8 + j) * 256];
        #pragma unroll
        for (int j = 0; j < 8; ++j) au += ag[o2 * 16 + j] * wa[j];
        if (o2 < 7) {
            #pragma unroll
            for (int j = 0; j < 8; ++j) wa[j] = U2c[(size_t)(o2 * 16 + 16 + j) * 256];
        }
        #pragma unroll
        for (int j = 0; j < 8; ++j) au += ag[o2 * 16 + 8 + j] * wb[j];
    }
    __syncthreads();
    sc[rq * 256 + c] = au;
    __syncthreads();
    return sc[c] + sc[256 + c] + updB[i * 256 + c];
}

__global__ __launch_bounds__(512) void fused_k(
    const float* __restrict__ feat,   // [16][128][256]
    const float* __restrict__ mask,   // [16][128]
    const float* __restrict__ aggW,   // [3][256][256]
    const float* __restrict__ aggB,   // [3][256]
    const float* __restrict__ attnW,  // [3][256][512]
    const float* __restrict__ updW,   // [3][256][512]
    const float* __restrict__ updB,   // [3][256]
    float* __restrict__ WtB,          // 12 * 65536 (k-major transposes)
    float* __restrict__ part,         // 2 * 256 * 768
    unsigned* flags, unsigned* rel,
    float* __restrict__ out)
{
    __shared__ float ldsa[5888];      // hidl[2048] | xl[2048] | sc[1536] | aggl[256]
    float* hidl = ldsa;
    float* xl   = ldsa + 2048;
    float* sc   = ldsa + 4096;
    float* aggl = ldsa + 5632;

    const int bid = blockIdx.x;
    const int tid = threadIdx.x;
    const int c  = tid & 255;
    const int rq = tid >> 8;                       // wave-uniform
    const int b  = bid >> 4, jj = bid & 15;
    const int rbase = b * 128 + jj * 8 + rq * 4;   // thread's first row

    // ---- P0: transpose 12 weight mats to k-major (blocks 0..191)
    if (bid < 192) {
        const int m = bid >> 4, t = bid & 15, tr = t >> 2, tc = t & 3;
        const float* src; int stride, off;
        if (m < 3)      { src = aggW  + (size_t)m * 65536;        stride = 256; off = 0;   }
        else if (m < 6) { src = attnW + (size_t)(m - 3) * 131072; stride = 512; off = 0;   }
        else if (m < 9) { src = updW  + (size_t)(m - 6) * 131072; stride = 512; off = 0;   }
        else            { src = updW  + (size_t)(m - 9) * 131072; stride = 512; off = 256; }
        float* dst = WtB + (size_t)m * 65536;
        #pragma unroll
        for (int it = 0; it < 2; ++it) {
            const int j = it * 512 + tid, row = j >> 4, q = (j & 15) * 4;
            const float4 v = *(const float4*)(src + (size_t)(tr * 64 + row) * stride + off + tc * 64 + q);
            ldsa[row * 65 + q + 0] = v.x; ldsa[row * 65 + q + 1] = v.y;
            ldsa[row * 65 + q + 2] = v.z; ldsa[row * 65 + q + 3] = v.w;
        }
        __syncthreads();
        #pragma unroll
        for (int it = 0; it < 2; ++it) {
            const int j = it * 512 + tid, kl = j >> 4, cq = (j & 15) * 4;
            float4 v;
            v.x = ldsa[(cq + 0) * 65 + kl]; v.y = ldsa[(cq + 1) * 65 + kl];
            v.z = ldsa[(cq + 2) * 65 + kl]; v.w = ldsa[(cq + 3) * 65 + kl];
            *(float4*)(dst + (size_t)(tc * 64 + kl) * 256 + tr * 64 + cq) = v;
        }
    }
    gridbar(1, flags, rel, bid, true);   // fence: flush transpose, kill poison

    float xu0 = 0.f, xu1 = 0.f, xu2 = 0.f, xu3 = 0.f;
    float accU = 0.f;

    for (int i = 0; i < 3; ++i) {
        if (i > 0)
            accU = phaseB(i - 1, b, c, rq, part, WtB, updB, sc, aggl);

        // ---- build hid rows in LDS: layout [k=c][8 rows]
        if (i == 0) {
            #pragma unroll
            for (int r = 0; r < 4; ++r)
                hidl[c * 8 + rq * 4 + r] =
                    feat[(size_t)(rbase + r) * 256 + c] * mask[rbase + r];
        } else {
            const float xur[4] = {xu0, xu1, xu2, xu3};
            #pragma unroll
            for (int r = 0; r < 4; ++r)
                hidl[c * 8 + rq * 4 + r] = (xur[r] + accU) * mask[rbase + r];
        }
        __syncthreads();

        // ---- P1: x = hid @ aggW^T + aggB (depth-2 octet register pipeline)
        {
            const float* Wc = WtB + (size_t)i * 65536 + c;
            float wa[8], wb[8];
            #pragma unroll
            for (int j = 0; j < 8; ++j) wa[j] = Wc[(size_t)j * 256];
            v2f a01 = {0.f, 0.f}, a23 = {0.f, 0.f};
            for (int o2 = 0; o2 < 16; ++o2) {
                #pragma unroll
                for (int j = 0; j < 8; ++j) wb[j] = Wc[(size_t)(o2 * 16 + 8 + j) * 256];
                #pragma unroll
                for (int j = 0; j < 8; ++j) {
                    const float4 h = *(const float4*)&hidl[(o2 * 16 + j) * 8 + rq * 4];
                    a01 += (v2f){h.x, h.y} * wa[j];
                    a23 += (v2f){h.z, h.w} * wa[j];
                }
                if (o2 < 15) {
                    #pragma unroll
                    for (int j = 0; j < 8; ++j) wa[j] = Wc[(size_t)(o2 * 16 + 16 + j) * 256];
                }
                #pragma unroll
                for (int j = 0; j < 8; ++j) {
                    const float4 h = *(const float4*)&hidl[(o2 * 16 + 8 + j) * 8 + rq * 4];
                    a01 += (v2f){h.x, h.y} * wb[j];
                    a23 += (v2f){h.z, h.w} * wb[j];
                }
            }
            const float bb = aggB[i * 256 + c];
            *(float4*)&xl[c * 8 + rq * 4] =
                make_float4(a01.x + bb, a01.y + bb, a23.x + bb, a23.y + bb);
        }
        __syncthreads();

        // ---- P2: p = x@W1^T, xU1 = x@U1^T (both streams pipelined)
        v2f p01 = {0.f, 0.f}, p23 = {0.f, 0.f};
        {
            const float* W1c = WtB + (size_t)(3 + i) * 65536 + c;
            const float* U1c = WtB + (size_t)(6 + i) * 65536 + c;
            float w1a[8], w1b[8], u1a[8], u1b[8];
            #pragma unroll
            for (int j = 0; j < 8; ++j) {
                w1a[j] = W1c[(size_t)j * 256];
                u1a[j] = U1c[(size_t)j * 256];
            }
            v2f q01 = {0.f, 0.f}, q23 = {0.f, 0.f};
            for (int o2 = 0; o2 < 16; ++o2) {
                #pragma unroll
                for (int j = 0; j < 8; ++j) {
                    w1b[j] = W1c[(size_t)(o2 * 16 + 8 + j) * 256];
                    u1b[j] = U1c[(size_t)(o2 * 16 + 8 + j) * 256];
                }
                #pragma unroll
                for (int j = 0; j < 8; ++j) {
                    const float4 xk = *(const float4*)&xl[(o2 * 16 + j) * 8 + rq * 4];
                    p01 += (v2f){xk.x, xk.y} * w1a[j];
                    p23 += (v2f){xk.z, xk.w} * w1a[j];
                    q01 += (v2f){xk.x, xk.y} * u1a[j];
                    q23 += (v2f){xk.z, xk.w} * u1a[j];
                }
                if (o2 < 15) {
                    #pragma unroll
                    for (int j = 0; j < 8; ++j) {
                        w1a[j] = W1c[(size_t)(o2 * 16 + 16 + j) * 256];
                        u1a[j] = U1c[(size_t)(o2 * 16 + 16 + j) * 256];
                    }
                }
                #pragma unroll
                for (int j = 0; j < 8; ++j) {
                    const float4 xk = *(const float4*)&xl[(o2 * 16 + 8 + j) * 8 + rq * 4];
                    p01 += (v2f){xk.x, xk.y} * w1b[j];
                    p23 += (v2f){xk.z, xk.w} * w1b[j];
                    q01 += (v2f){xk.x, xk.y} * u1b[j];
                    q23 += (v2f){xk.z, xk.w} * u1b[j];
                }
            }
            xu0 = q01.x; xu1 = q01.y; xu2 = q23.x; xu3 = q23.y;
        }

        // ---- online-softmax partials over this thread's 4 rows
        {
            const float4 x4 = *(const float4*)&xl[c * 8 + rq * 4];
            const float m4 = fmaxf(fmaxf(p01.x, p01.y), fmaxf(p23.x, p23.y));
            const float e0 = __expf(p01.x - m4), e1 = __expf(p01.y - m4);
            const float e2 = __expf(p23.x - m4), e3 = __expf(p23.y - m4);
            const float d4 = e0 + e1 + e2 + e3;
            const float n4 = e0 * x4.x + e1 * x4.y + e2 * x4.z + e3 * x4.w;
            sc[rq * 256 + c] = m4;
            sc[512 + rq * 256 + c] = d4;
            sc[1024 + rq * 256 + c] = n4;
        }
        __syncthreads();
        if (rq == 0) {
            const float m0 = sc[c], m1 = sc[256 + c];
            const float Mx = fmaxf(m0, m1);
            const float s0 = __expf(m0 - Mx), s1 = __expf(m1 - Mx);
            const float dd = sc[512 + c] * s0 + sc[768 + c] * s1;
            const float nn = sc[1024 + c] * s0 + sc[1280 + c] * s1;
            float* pb = part + (size_t)((i & 1) * 256 + bid) * 768;
            AG_ST(pb + c, Mx);
            AG_ST(pb + 256 + c, dd);
            AG_ST(pb + 512 + c, nn);
        }
        gridbar(i + 2, flags, rel, bid, false);   // no fence: L2 stays warm
    }

    // ---- final combine + epilogue: out = xU1 + accU
    accU = phaseB(2, b, c, rq, part, WtB, updB, sc, aggl);
    const float xur[4] = {xu0, xu1, xu2, xu3};
    #pragma unroll
    for (int r = 0; r < 4; ++r)
        out[(size_t)(rbase + r) * 256 + c] = xur[r] + accU;
}

extern "C" void kernel_launch(void* const* d_in, const int* in_sizes, int n_in,
                              void* d_out, int out_size, void* d_ws, size_t ws_size,
                              hipStream_t stream) {
    const float* feat  = (const float*)d_in[0];
    const float* mask  = (const float*)d_in[1];
    const float* aggW  = (const float*)d_in[2];
    const float* aggB  = (const float*)d_in[3];
    const float* attnW = (const float*)d_in[4];
    // d_in[5] = attnB: cancels in softmax (constant along the s axis)
    const float* updW  = (const float*)d_in[6];
    const float* updB  = (const float*)d_in[7];

    float* WtB  = (float*)d_ws;                        // 12 * 65536 floats
    float* part = WtB + 12 * 65536;                    // 2 * 256 * 768 floats
    unsigned* flags = (unsigned*)(part + 2 * 256 * 768);
    unsigned* rel   = flags + NBLK * FPAD;

    fused_k<<<NBLK, 512, 0, stream>>>(
        feat, mask, aggW, aggB, attnW, updW, updB,
        WtB, part, flags, rel, (float*)d_out);
}